// Round 1
// baseline (162.450 us; speedup 1.0000x reference)
//
#include <hip/hip_runtime.h>
#include <stdint.h>

// ---------------------------------------------------------------------------
// WideAndDeep: B=16384, F=3, C=256, D=64, H=1024, ND=13
// R15: gemm_fused rewritten as the 256x256 8-phase schedule (T2 swizzle +
// T3/T4 counted vmcnt(4) + T5 setprio + T1 XCD swizzle). GEMM1 (K=224) and
// prep/sigmoid unchanged (2-barrier core proven at 181.9 us config).
// 8-phase stage order per iter (1 half-tile = 2 global_load_lds/thread/phase):
//   p1:A.O.h0  p2:A.O.h1  p3:B.E.h0  p4:B.E.h1[vmcnt4]
//   p5:A.E.h0  p6:A.E.h1  p7:B.O.h0  p8:B.O.h1[vmcnt4]
// Reads: E a(m0),b(n0)@p1 b(n1)@p2 a(m1)@p3 (p4 reg-reuse); O same @p5-8.
// FIFO proof: vmcnt(4) at p4 retires {prev p7,p8 (B.O), p1,p2 (A.O)} = all
// halves read in p5-p8; at p8 retires {p3..p6} = all halves read next p1-p4.
// ---------------------------------------------------------------------------

#define BATCH 16384
#define HDIM 1024
#define K1 224
#define DEEP_IN 205

typedef short bf16x8 __attribute__((ext_vector_type(8)));
typedef float f32x4 __attribute__((ext_vector_type(4)));
typedef uint16_t u16x8 __attribute__((ext_vector_type(8)));
typedef uint16_t u16x4 __attribute__((ext_vector_type(4)));

__device__ __forceinline__ uint16_t f2bf(float f) {
    uint32_t x;
    __builtin_memcpy(&x, &f, 4);
    uint32_t r = (x + 0x7fffu + ((x >> 16) & 1u)) >> 16;
    return (uint16_t)r;
}

__device__ __forceinline__ void async_ld16(const uint16_t* g, uint16_t* l) {
    __builtin_amdgcn_global_load_lds(
        (const __attribute__((address_space(1))) uint32_t*)g,
        (__attribute__((address_space(3))) uint32_t*)l, 16, 0, 0);
}

// ---------------------------------------------------------------------------
// prep: only what gemm_relu needs.
//   [0, 1792)     : build deep_x [B][224] bf16 (x8 vectorized)
//   [1792, 1904)  : W1 -> bf16, 205 -> 224 K-pad (x8)
// ---------------------------------------------------------------------------
__global__ __launch_bounds__(256) void prep_kernel(
    const int* __restrict__ sp, const float* __restrict__ dense,
    const float* __restrict__ emb, const float* __restrict__ W1,
    uint16_t* __restrict__ dx, uint16_t* __restrict__ W1b)
{
    const int bid = blockIdx.x;
    if (bid < 1792) {                      // ---- deep_x build (16384 x 28 vec8)
        int idx = bid * 256 + threadIdx.x; // < 458752
        int b = idx / 28, c0 = (idx - b * 28) * 8;
        u16x8 o;
        if (c0 < 192) {
            int f = c0 >> 6, cc = c0 & 63;
            int s = sp[b * 3 + f];
            const float* e = emb + (size_t)(((f << 8) + s) * 64 + cc);
            float4 v0 = *(const float4*)e;
            float4 v1 = *(const float4*)(e + 4);
            o[0] = f2bf(v0.x); o[1] = f2bf(v0.y); o[2] = f2bf(v0.z); o[3] = f2bf(v0.w);
            o[4] = f2bf(v1.x); o[5] = f2bf(v1.y); o[6] = f2bf(v1.z); o[7] = f2bf(v1.w);
        } else {
#pragma unroll
            for (int t = 0; t < 8; t++) {
                int c = c0 + t;
                o[t] = (c < DEEP_IN) ? f2bf(dense[b * 13 + (c - 192)])
                                     : (uint16_t)0;
            }
        }
        *(u16x8*)(dx + (size_t)b * K1 + c0) = o;
    } else {                               // ---- W1 convert, 205 -> 224
        int idx = (bid - 1792) * 256 + threadIdx.x;  // < 28672
        int n = idx / 28, c0 = (idx - n * 28) * 8;
        u16x8 o;
#pragma unroll
        for (int t = 0; t < 8; t++) {
            int c = c0 + t;
            o[t] = (c < DEEP_IN) ? f2bf(W1[n * DEEP_IN + c]) : (uint16_t)0;
        }
        *(u16x8*)(W1b + (size_t)n * K1 + c0) = o;
    }
}

// ---------------------------------------------------------------------------
// Shared GEMM core for GEMM1 (permuted B columns) — unchanged, proven.
// ---------------------------------------------------------------------------
#define GEMM_CORE(A_, B_, K_)                                                  \
    const int lane = tid & 63;                                                 \
    const int wave = tid >> 6;                                                 \
    const int wm = wave >> 2;                                                  \
    const int wn = wave & 3;                                                   \
    const int xcd = id & 7;                                                    \
    const int slot = id >> 3;                                                  \
    const int mbX = (M >> 7) >> 3;                                             \
    const int by = xcd * mbX + (slot >> 2);                                    \
    const int bx = slot & 3;                                                   \
    const int bm = by * 128;                                                   \
    const int bn = bx * 256;                                                   \
    const int rl = lane & 15, q = lane >> 4;                                   \
    f32x4 acc[4][4];                                                           \
    _Pragma("unroll") for (int i = 0; i < 4; i++)                              \
        _Pragma("unroll") for (int j = 0; j < 4; j++) acc[i][j] = (f32x4)0.f;  \
    const int cc0 = 2 * wave, cc1 = 2 * wave + 1;                              \
    const uint16_t* aS = A_ + (size_t)(bm + wave * 16 + rl) * K_ + q * 8;      \
    const uint16_t* bS0 = B_ + (size_t)(bn + (cc0 >> 2) * 64 + 4 * rl + (cc0 & 3)) * K_ + q * 8; \
    const uint16_t* bS1 = B_ + (size_t)(bn + (cc1 >> 2) * 64 + 4 * rl + (cc1 & 3)) * K_ + q * 8; \
    const int dA = wave * 512, dB0 = cc0 * 512, dB1 = cc1 * 512;               \
    async_ld16(aS, &Al[0][dA]);                                                \
    async_ld16(bS0, &Bl[0][dB0]);                                              \
    async_ld16(bS1, &Bl[0][dB1]);                                              \
    asm volatile("s_waitcnt vmcnt(0)" ::: "memory");                           \
    __syncthreads();                                                           \
    int p = 0;                                                                 \
    for (int k0 = 32; k0 < K_; k0 += 32) {                                     \
        async_ld16(aS + k0, &Al[p ^ 1][dA]);                                   \
        async_ld16(bS0 + k0, &Bl[p ^ 1][dB0]);                                 \
        async_ld16(bS1 + k0, &Bl[p ^ 1][dB1]);                                 \
        bf16x8 af[4], bfr[4];                                                  \
        _Pragma("unroll") for (int i = 0; i < 4; i++)                          \
            af[i] = *(const bf16x8*)&Al[p][(wm * 4 + i) * 512 + lane * 8];     \
        _Pragma("unroll") for (int j = 0; j < 4; j++)                          \
            bfr[j] = *(const bf16x8*)&Bl[p][(wn * 4 + j) * 512 + lane * 8];    \
        _Pragma("unroll") for (int i = 0; i < 4; i++)                          \
            _Pragma("unroll") for (int j = 0; j < 4; j++)                      \
                acc[i][j] = __builtin_amdgcn_mfma_f32_16x16x32_bf16(           \
                    af[i], bfr[j], acc[i][j], 0, 0, 0);                        \
        asm volatile("s_waitcnt vmcnt(0)" ::: "memory");                       \
        __syncthreads();                                                       \
        p ^= 1;                                                                \
    }                                                                          \
    {                                                                          \
        bf16x8 af[4], bfr[4];                                                  \
        _Pragma("unroll") for (int i = 0; i < 4; i++)                          \
            af[i] = *(const bf16x8*)&Al[p][(wm * 4 + i) * 512 + lane * 8];     \
        _Pragma("unroll") for (int j = 0; j < 4; j++)                          \
            bfr[j] = *(const bf16x8*)&Bl[p][(wn * 4 + j) * 512 + lane * 8];    \
        _Pragma("unroll") for (int i = 0; i < 4; i++)                          \
            _Pragma("unroll") for (int j = 0; j < 4; j++)                      \
                acc[i][j] = __builtin_amdgcn_mfma_f32_16x16x32_bf16(           \
                    af[i], bfr[j], acc[i][j], 0, 0, 0);                        \
    }

// ---------------------------------------------------------------------------
// gemm_relu: [0,512) h1 = relu(dxp @ W1b^T + b1), u16x4 packed row stores;
//            [512,768) W2 -> bf16 convert; [768,800) wide path + b3 seed.
// ---------------------------------------------------------------------------
__global__ __launch_bounds__(512, 4) void gemm_relu(
    const uint16_t* __restrict__ A, const uint16_t* __restrict__ Bw,
    const float* __restrict__ bias, uint16_t* __restrict__ C,
    const float* __restrict__ W2, uint16_t* __restrict__ W2b,
    const int* __restrict__ sp, const float* __restrict__ dense,
    const float* __restrict__ ww, const float* __restrict__ wb,
    const float* __restrict__ b3, float* __restrict__ wide,
    int M, int N, int K)
{
    const int id = blockIdx.x;
    const int tid = threadIdx.x;

    if (id >= 512) {
        if (id < 768) {                    // ---- W2 convert (x8)
            int k = (id - 512) * 512 + tid;    // < 131072
            const float* src = W2 + (size_t)k * 8;
            float4 v0 = *(const float4*)src;
            float4 v1 = *(const float4*)(src + 4);
            u16x8 o;
            o[0] = f2bf(v0.x); o[1] = f2bf(v0.y); o[2] = f2bf(v0.z); o[3] = f2bf(v0.w);
            o[4] = f2bf(v1.x); o[5] = f2bf(v1.y); o[6] = f2bf(v1.z); o[7] = f2bf(v1.w);
            *(u16x8*)(W2b + (size_t)k * 8) = o;
        } else {                           // ---- wide path (+ b3 seed)
            int b = (id - 768) * 512 + tid;    // < 16384
            int s0 = sp[b * 3], s1 = sp[b * 3 + 1], s2 = sp[b * 3 + 2];
            float w = wb[0] + b3[0];
            w += ww[s0] + ww[256 + s1] + ww[512 + s2];
            w += ww[768    + s0 * 3 + s1];
            w += ww[66304  + s0 * 3 + s2];
            w += ww[131840 + s1 * 3 + s2];
            w += ww[197376 + (s0 * 3 + s1) * 3 + s2];
            const float* wd = ww + 16974592;
            float acc2 = 0.f;
#pragma unroll
            for (int j = 0; j < 13; j++) acc2 += dense[b * 13 + j] * wd[j];
            wide[b] = w + acc2;
        }
        return;
    }

    __shared__ __align__(16) uint16_t Al[2][4096];   // 128 x 32 dbuf
    __shared__ __align__(16) uint16_t Bl[2][8192];   // 256 x 32 dbuf
    GEMM_CORE(A, Bw, K)

    float bv[4];
#pragma unroll
    for (int j = 0; j < 4; j++) bv[j] = bias[bn + wn * 64 + 4 * rl + j];
#pragma unroll
    for (int i = 0; i < 4; i++) {
#pragma unroll
        for (int r = 0; r < 4; r++) {
            int m = bm + wm * 64 + i * 16 + q * 4 + r;
            u16x4 o;
#pragma unroll
            for (int j = 0; j < 4; j++)
                o[j] = f2bf(fmaxf(acc[i][j][r] + bv[j], 0.f));
            *(u16x4*)&C[(size_t)m * N + bn + wn * 64 + 4 * rl] = o;
        }
    }
}

// ---------------------------------------------------------------------------
// gemm_fused8: 256x256 8-phase schedule for GEMM2 (M=16384,N=1024,K=1024).
// 8 waves 2m x 4n, wave tile 128x64, BK=64, 128 KiB LDS (2 K-tile dbuf).
// LDS element map: AE=0 AO=16384 BE=32768 BO=49152; each region is
// [2 halves][128 rows][64 cols], row r's column bytes XOR-swizzled by
// (r&7)<<4 (inverse-swizzled global source, linear global_load_lds dest).
// Raw s_barrier (no vmcnt drain); vmcnt(4) only at phases 4 & 8.
// Epilogue: relu(acc+b2).W3 -> shfl-reduce over 16 lanes -> atomicAdd(wide).
// ---------------------------------------------------------------------------
#define BAR8() do { asm volatile("" ::: "memory");                             \
    __builtin_amdgcn_s_barrier();                                              \
    asm volatile("" ::: "memory"); } while (0)
#define VM4() asm volatile("s_waitcnt vmcnt(4)" ::: "memory")

#define STG8(grow, regoff, h, kt) do {                                         \
    const uint16_t* g_ = (grow) + (size_t)((h) * 128) * (size_t)K + (kt);      \
    async_ld16(g_, &lds[(regoff) + (h) * 8192 + wave * 512]);                  \
    async_ld16(g_ + (size_t)64 * (size_t)K,                                    \
               &lds[(regoff) + (h) * 8192 + 4096 + wave * 512]);               \
} while (0)

#define LDA8(base, msub) do {                                                  \
    _Pragma("unroll") for (int mt = 0; mt < 4; mt++) {                         \
        int ro_ = (base) + ((msub) * 64 + mt * 16) * 64;                       \
        af[mt][0] = *(const bf16x8*)&lds[ro_ + kc0];                           \
        af[mt][1] = *(const bf16x8*)&lds[ro_ + kc1];                           \
    } } while (0)

#define LDB8(dst, base, nsub) do {                                             \
    _Pragma("unroll") for (int nt = 0; nt < 2; nt++) {                         \
        int ro_ = (base) + ((nsub) * 32 + nt * 16) * 64;                       \
        dst[nt][0] = *(const bf16x8*)&lds[ro_ + kc0];                          \
        dst[nt][1] = *(const bf16x8*)&lds[ro_ + kc1];                          \
    } } while (0)

#define MM8(msub, nsub, BF) do {                                               \
    __builtin_amdgcn_s_setprio(1);                                             \
    _Pragma("unroll") for (int mt = 0; mt < 4; mt++)                           \
    _Pragma("unroll") for (int nt = 0; nt < 2; nt++) {                         \
        acc[(msub)*4+mt][(nsub)*2+nt] = __builtin_amdgcn_mfma_f32_16x16x32_bf16( \
            af[mt][0], BF[nt][0], acc[(msub)*4+mt][(nsub)*2+nt], 0, 0, 0);     \
        acc[(msub)*4+mt][(nsub)*2+nt] = __builtin_amdgcn_mfma_f32_16x16x32_bf16( \
            af[mt][1], BF[nt][1], acc[(msub)*4+mt][(nsub)*2+nt], 0, 0, 0);     \
    }                                                                          \
    __builtin_amdgcn_s_setprio(0); } while (0)

__global__ __launch_bounds__(512, 2) void gemm_fused8(
    const uint16_t* __restrict__ A, const uint16_t* __restrict__ Bw,
    const float* __restrict__ bias, const float* __restrict__ W3,
    float* __restrict__ outacc, int M, int N, int K)
{
    __shared__ __align__(16) uint16_t lds[65536];   // 128 KiB
    const int tid = threadIdx.x;
    const int lane = tid & 63, wave = tid >> 6;
    const int wm = wave >> 2, wn = wave & 3;
    // XCD swizzle: grid 256 (64 by x 4 bx) -> 8 XCDs x 32; A-panel reuse in-XCD
    const int id = blockIdx.x;
    const int wg = (id & 7) * 32 + (id >> 3);
    const int by = wg >> 2, bx = wg & 3;
    const int bm = by * 256, bn = bx * 256;

    const int lam = lane & 15, lad = lane >> 4;
    const int sw = (lane & 7) << 4;                 // byte swizzle
    const int kc0 = ((lad * 16) ^ sw) >> 1;         // elem col, k-step 0
    const int kc1 = ((64 + lad * 16) ^ sw) >> 1;    // elem col, k-step 1
    const int aBE = wm * 8192 + lam * 64;           // A half(wm), E region
    const int aBO = aBE + 16384;
    const int bBE = 32768 + (wn >> 1) * 8192 + ((wn & 1) * 64 + lam) * 64;
    const int bBO = bBE + 16384;

    // staging source: thread t covers row (t>>3) of each 64-row load slab;
    // source col pre-swizzled so linear LDS dest holds the swizzled layout.
    const int trow = tid >> 3;
    const int csel = ((tid & 7) ^ (trow & 7)) << 3;     // elements
    const uint16_t* aRow = A + (size_t)(bm + trow) * K + csel;
    const uint16_t* bRow = Bw + (size_t)(bn + trow) * K + csel;

    f32x4 acc[8][4];
#pragma unroll
    for (int i = 0; i < 8; i++)
#pragma unroll
        for (int j = 0; j < 4; j++) acc[i][j] = (f32x4)0.f;
    bf16x8 af[4][2], bf0[2][2], bf1[2][2];

    const int NT = K >> 6;   // 16 K-tiles
    const int NI = K >> 7;   // 8 iterations (2 K-tiles each)

    // Prologue: tile0 -> E (A,B), tile1 -> B.O ; leave B.O in flight.
    STG8(aRow, 0, 0, 0);     STG8(aRow, 0, 1, 0);
    STG8(bRow, 32768, 0, 0); STG8(bRow, 32768, 1, 0);
    STG8(bRow, 49152, 0, 64); STG8(bRow, 49152, 1, 64);
    VM4();
    BAR8();

    for (int it = 0; it < NI; ++it) {
        const int k1 = (2 * it + 1) * 64;           // tile 2it+1 (<= 15)
        const int t2 = 2 * it + 2, t3 = 2 * it + 3;
        const int k2 = (t2 < NT ? t2 : 0) * 64;     // wrap: dead loads in-bounds
        const int k3 = (t3 < NT ? t3 : 0) * 64;
        // p1: E(m0,n0); stage A.O.h0(tile 2it+1)
        LDA8(aBE, 0); LDB8(bf0, bBE, 0); STG8(aRow, 16384, 0, k1);
        BAR8(); MM8(0, 0, bf0); BAR8();
        // p2: E(m0,n1); stage A.O.h1
        LDB8(bf1, bBE, 1); STG8(aRow, 16384, 1, k1);
        BAR8(); MM8(0, 1, bf1); BAR8();
        // p3: E(m1,n1); stage B.E.h0(tile 2it+2)
        LDA8(aBE, 1); STG8(bRow, 32768, 0, k2);
        BAR8(); MM8(1, 1, bf1); BAR8();
        // p4: E(m1,n0) reg-reuse; stage B.E.h1; counted wait
        STG8(bRow, 32768, 1, k2);
        BAR8(); MM8(1, 0, bf0); VM4(); BAR8();
        // p5: O(m0,n0); stage A.E.h0(tile 2it+2)
        LDA8(aBO, 0); LDB8(bf0, bBO, 0); STG8(aRow, 0, 0, k2);
        BAR8(); MM8(0, 0, bf0); BAR8();
        // p6: O(m0,n1); stage A.E.h1
        LDB8(bf1, bBO, 1); STG8(aRow, 0, 1, k2);
        BAR8(); MM8(0, 1, bf1); BAR8();
        // p7: O(m1,n1); stage B.O.h0(tile 2it+3)
        LDA8(aBO, 1); STG8(bRow, 49152, 0, k3);
        BAR8(); MM8(1, 1, bf1); BAR8();
        // p8: O(m1,n0) reg-reuse; stage B.O.h1; counted wait
        STG8(bRow, 49152, 1, k3);
        BAR8(); MM8(1, 0, bf0); VM4(); BAR8();
    }

    // Epilogue: pt = sum_n relu(acc+b2[n])*W3[n]; reduce 16 lanes; atomicAdd.
    float bv[4], w3v[4];
#pragma unroll
    for (int jn = 0; jn < 4; jn++) {
        int n = bn + wn * 64 + jn * 16 + lam;
        bv[jn] = bias[n];
        w3v[jn] = W3[n];
    }
#pragma unroll
    for (int im = 0; im < 8; im++) {
#pragma unroll
        for (int r = 0; r < 4; r++) {
            float pt = 0.f;
#pragma unroll
            for (int jn = 0; jn < 4; jn++)
                pt += fmaxf(acc[im][jn][r] + bv[jn], 0.f) * w3v[jn];
            pt += __shfl_xor(pt, 1);
            pt += __shfl_xor(pt, 2);
            pt += __shfl_xor(pt, 4);
            pt += __shfl_xor(pt, 8);
            if (lam == 0) {
                int m = bm + wm * 128 + im * 16 + lad * 4 + r;
                atomicAdd(&outacc[m], pt);
            }
        }
    }
}

// ---------------------------------------------------------------------------
// Sigmoid over the accumulated logits. Grid 64 x 256.
// ---------------------------------------------------------------------------
__global__ __launch_bounds__(256) void sigmoid_kernel(
    const float* __restrict__ outacc, float* __restrict__ out)
{
    int b = blockIdx.x * 256 + threadIdx.x;
    out[b] = 1.f / (1.f + __expf(-outacc[b]));
}

// ---------------------------------------------------------------------------
extern "C" void kernel_launch(void* const* d_in, const int* in_sizes, int n_in,
                              void* d_out, int out_size, void* d_ws, size_t ws_size,
                              hipStream_t stream) {
    const int*   sp    = (const int*)d_in[0];
    const float* dense = (const float*)d_in[1];
    const float* ww    = (const float*)d_in[2];
    const float* wb    = (const float*)d_in[3];
    const float* emb   = (const float*)d_in[4];
    const float* W1    = (const float*)d_in[5];
    const float* b1    = (const float*)d_in[6];
    const float* W2    = (const float*)d_in[7];
    const float* b2    = (const float*)d_in[8];
    const float* W3    = (const float*)d_in[9];
    const float* b3    = (const float*)d_in[10];
    float* out = (float*)d_out;

    char* ws = (char*)d_ws;
    float*    wide = (float*)ws;                       //     65,536 B
    uint16_t* dxp  = (uint16_t*)(ws + 65536);          //  7,340,032 B (16384x224)
    uint16_t* W1b  = (uint16_t*)(ws + 7405568);        //    458,752 B (1024x224)
    uint16_t* W2b  = (uint16_t*)(ws + 7864320);        //  2,097,152 B
    uint16_t* h1   = (uint16_t*)(ws + 9961472);        // 33,554,432 B -> 43,515,904 total

    prep_kernel<<<1904, 256, 0, stream>>>(sp, dense, emb, W1, dxp, W1b);
    gemm_relu<<<800, 512, 0, stream>>>(
        dxp, W1b, b1, h1, W2, W2b, sp, dense, ww, wb, b3, wide,
        BATCH, HDIM, K1);
    gemm_fused8<<<(BATCH / 256) * (HDIM / 256), 512, 0, stream>>>(
        h1, W2b, b2, W3, wide, BATCH, HDIM, HDIM);
    sigmoid_kernel<<<BATCH / 256, 256, 0, stream>>>(wide, out);
}

// Round 2
// 160.687 us; speedup vs baseline: 1.0110x; 1.0110x over previous
//
#include <hip/hip_runtime.h>
#include <stdint.h>

// ---------------------------------------------------------------------------
// WideAndDeep: B=16384, F=3, C=256, D=64, H=1024, ND=13
// R16: BOTH GEMMs on the 256x256 8-phase schedule (T2 swizzle + T3/T4
// counted vmcnt(4) + T5 setprio + T1 XCD swizzle). GEMM1 K padded 205->256
// (zero-pad, exact); B-row permutation (prow=4*(t&15)+(t>>4)) relabels
// output cols so each lane owns 4 consecutive n -> packed u16x4 h1 stores.
// W2-convert + wide path moved into prep (GEMM grids are 1 block/CU with
// 128 KiB LDS; side jobs there would serialize).
// 8-phase stage order per iter (1 half-tile = 2 global_load_lds/thread/phase):
//   p1:A.O.h0  p2:A.O.h1  p3:B.E.h0  p4:B.E.h1[vmcnt4]
//   p5:A.E.h0  p6:A.E.h1  p7:B.O.h0  p8:B.O.h1[vmcnt4]
// FIFO proof: vmcnt(4) at p4 retires {prev p7,p8 (B.O), p1,p2 (A.O)} = all
// halves read in p5-p8; at p8 retires {p3..p6} = all halves read next p1-p4.
// K=256 (NI=2) wrap-loads re-read tile 0 (in-bounds, L2-hot, keeps counts).
// ---------------------------------------------------------------------------

#define BATCH 16384
#define HDIM 1024
#define K1 256
#define DEEP_IN 205

typedef short bf16x8 __attribute__((ext_vector_type(8)));
typedef float f32x4 __attribute__((ext_vector_type(4)));
typedef uint16_t u16x8 __attribute__((ext_vector_type(8)));
typedef uint16_t u16x4 __attribute__((ext_vector_type(4)));

__device__ __forceinline__ uint16_t f2bf(float f) {
    uint32_t x;
    __builtin_memcpy(&x, &f, 4);
    uint32_t r = (x + 0x7fffu + ((x >> 16) & 1u)) >> 16;
    return (uint16_t)r;
}

__device__ __forceinline__ void async_ld16(const uint16_t* g, uint16_t* l) {
    __builtin_amdgcn_global_load_lds(
        (const __attribute__((address_space(1))) uint32_t*)g,
        (__attribute__((address_space(3))) uint32_t*)l, 16, 0, 0);
}

// ---------------------------------------------------------------------------
// prep: everything the GEMMs need, one 256-thread elementwise kernel.
//   [0, 2048)    : deep_x [B][256] bf16 (x8), cols 205..255 = 0
//   [2048, 2176) : W1 -> bf16, 205 -> 256 K-pad (x8)
//   [2176, 2688) : W2 -> bf16 (x8)
//   [2688, 2752) : wide path (sparse gathers + dense dot) + b3 seed
// ---------------------------------------------------------------------------
__global__ __launch_bounds__(256) void prep_kernel(
    const int* __restrict__ sp, const float* __restrict__ dense,
    const float* __restrict__ emb, const float* __restrict__ W1,
    const float* __restrict__ W2, const float* __restrict__ ww,
    const float* __restrict__ wb, const float* __restrict__ b3,
    uint16_t* __restrict__ dx, uint16_t* __restrict__ W1b,
    uint16_t* __restrict__ W2b, float* __restrict__ wide)
{
    const int bid = blockIdx.x;
    const int tid = threadIdx.x;
    if (bid < 2048) {                      // ---- deep_x build (16384 x 32 vec8)
        int idx = bid * 256 + tid;         // < 524288
        int b = idx >> 5, c0 = (idx & 31) * 8;
        u16x8 o;
        if (c0 < 192) {
            int f = c0 >> 6, cc = c0 & 63;
            int s = sp[b * 3 + f];
            const float* e = emb + (size_t)(((f << 8) + s) * 64 + cc);
            float4 v0 = *(const float4*)e;
            float4 v1 = *(const float4*)(e + 4);
            o[0] = f2bf(v0.x); o[1] = f2bf(v0.y); o[2] = f2bf(v0.z); o[3] = f2bf(v0.w);
            o[4] = f2bf(v1.x); o[5] = f2bf(v1.y); o[6] = f2bf(v1.z); o[7] = f2bf(v1.w);
        } else {
#pragma unroll
            for (int t = 0; t < 8; t++) {
                int c = c0 + t;
                o[t] = (c < DEEP_IN) ? f2bf(dense[b * 13 + (c - 192)])
                                     : (uint16_t)0;
            }
        }
        *(u16x8*)(dx + (size_t)b * K1 + c0) = o;
    } else if (bid < 2176) {               // ---- W1 convert, 205 -> 256
        int idx = (bid - 2048) * 256 + tid;    // < 32768
        int n = idx >> 5, c0 = (idx & 31) * 8;
        u16x8 o;
#pragma unroll
        for (int t = 0; t < 8; t++) {
            int c = c0 + t;
            o[t] = (c < DEEP_IN) ? f2bf(W1[n * DEEP_IN + c]) : (uint16_t)0;
        }
        *(u16x8*)(W1b + (size_t)n * K1 + c0) = o;
    } else if (bid < 2688) {               // ---- W2 convert (x8)
        int k = (bid - 2176) * 256 + tid;      // < 131072
        const float* src = W2 + (size_t)k * 8;
        float4 v0 = *(const float4*)src;
        float4 v1 = *(const float4*)(src + 4);
        u16x8 o;
        o[0] = f2bf(v0.x); o[1] = f2bf(v0.y); o[2] = f2bf(v0.z); o[3] = f2bf(v0.w);
        o[4] = f2bf(v1.x); o[5] = f2bf(v1.y); o[6] = f2bf(v1.z); o[7] = f2bf(v1.w);
        *(u16x8*)(W2b + (size_t)k * 8) = o;
    } else {                               // ---- wide path (+ b3 seed)
        int b = (bid - 2688) * 256 + tid;      // < 16384
        int s0 = sp[b * 3], s1 = sp[b * 3 + 1], s2 = sp[b * 3 + 2];
        float w = wb[0] + b3[0];
        w += ww[s0] + ww[256 + s1] + ww[512 + s2];
        w += ww[768    + s0 * 3 + s1];
        w += ww[66304  + s0 * 3 + s2];
        w += ww[131840 + s1 * 3 + s2];
        w += ww[197376 + (s0 * 3 + s1) * 3 + s2];
        const float* wd = ww + 16974592;
        float acc2 = 0.f;
#pragma unroll
        for (int j = 0; j < 13; j++) acc2 += dense[b * 13 + j] * wd[j];
        wide[b] = w + acc2;
    }
}

// ---------------------------------------------------------------------------
// Shared 8-phase GEMM core. 256x256 tile, 8 waves 2m x 4n, wave tile 128x64,
// BK=64, 128 KiB LDS (2 K-tile dbuf). LDS element map: AE=0 AO=16384
// BE=32768 BO=49152; each region [2 halves][128 rows][64 cols], row r's
// column bytes XOR-swizzled by (r&7)<<4 (inverse-swizzled global source,
// linear global_load_lds dest). Raw s_barrier; vmcnt(4) only at p4 & p8.
// ---------------------------------------------------------------------------
#define BAR8() do { asm volatile("" ::: "memory");                             \
    __builtin_amdgcn_s_barrier();                                              \
    asm volatile("" ::: "memory"); } while (0)
#define VM4() asm volatile("s_waitcnt vmcnt(4)" ::: "memory")

#define STG8(grow, regoff, h, kt) do {                                         \
    const uint16_t* g_ = (grow) + (size_t)((h) * 128) * (size_t)K + (kt);      \
    async_ld16(g_, &lds[(regoff) + (h) * 8192 + wave * 512]);                  \
    async_ld16(g_ + (size_t)64 * (size_t)K,                                    \
               &lds[(regoff) + (h) * 8192 + 4096 + wave * 512]);               \
} while (0)

#define LDA8(base, msub) do {                                                  \
    _Pragma("unroll") for (int mt = 0; mt < 4; mt++) {                         \
        int ro_ = (base) + ((msub) * 64 + mt * 16) * 64;                       \
        af[mt][0] = *(const bf16x8*)&lds[ro_ + kc0];                           \
        af[mt][1] = *(const bf16x8*)&lds[ro_ + kc1];                           \
    } } while (0)

#define LDB8(dst, base, nsub) do {                                             \
    _Pragma("unroll") for (int nt = 0; nt < 2; nt++) {                         \
        int ro_ = (base) + ((nsub) * 32 + nt * 16) * 64;                       \
        dst[nt][0] = *(const bf16x8*)&lds[ro_ + kc0];                          \
        dst[nt][1] = *(const bf16x8*)&lds[ro_ + kc1];                          \
    } } while (0)

#define MM8(msub, nsub, BF) do {                                               \
    __builtin_amdgcn_s_setprio(1);                                             \
    _Pragma("unroll") for (int mt = 0; mt < 4; mt++)                           \
    _Pragma("unroll") for (int nt = 0; nt < 2; nt++) {                         \
        acc[(msub)*4+mt][(nsub)*2+nt] = __builtin_amdgcn_mfma_f32_16x16x32_bf16( \
            af[mt][0], BF[nt][0], acc[(msub)*4+mt][(nsub)*2+nt], 0, 0, 0);     \
        acc[(msub)*4+mt][(nsub)*2+nt] = __builtin_amdgcn_mfma_f32_16x16x32_bf16( \
            af[mt][1], BF[nt][1], acc[(msub)*4+mt][(nsub)*2+nt], 0, 0, 0);     \
    }                                                                          \
    __builtin_amdgcn_s_setprio(0); } while (0)

#define GEMM8_DECLS()                                                          \
    const int tid = threadIdx.x;                                               \
    const int lane = tid & 63, wave = tid >> 6;                                \
    const int wm = wave >> 2, wn = wave & 3;                                   \
    const int id = blockIdx.x;                                                 \
    const int wg = (id & 7) * 32 + (id >> 3);                                  \
    const int by = wg >> 2, bx = wg & 3;                                       \
    const int bm = by * 256, bn = bx * 256;                                    \
    const int lam = lane & 15, lad = lane >> 4;                                \
    const int sw = (lane & 7) << 4;                                            \
    const int kc0 = ((lad * 16) ^ sw) >> 1;                                    \
    const int kc1 = ((64 + lad * 16) ^ sw) >> 1;                               \
    const int aBE = wm * 8192 + lam * 64;                                      \
    const int aBO = aBE + 16384;                                               \
    const int bBE = 32768 + (wn >> 1) * 8192 + ((wn & 1) * 64 + lam) * 64;     \
    const int bBO = bBE + 16384;                                               \
    const int trow = tid >> 3;                                                 \
    const int csel = ((tid & 7) ^ (trow & 7)) << 3;

#define GEMM8_MAIN()                                                           \
    f32x4 acc[8][4];                                                           \
    _Pragma("unroll") for (int i = 0; i < 8; i++)                              \
        _Pragma("unroll") for (int j = 0; j < 4; j++) acc[i][j] = (f32x4)0.f;  \
    bf16x8 af[4][2], bf0[2][2], bf1[2][2];                                     \
    const int NT = K >> 6;                                                     \
    const int NI = K >> 7;                                                     \
    STG8(aRow, 0, 0, 0);     STG8(aRow, 0, 1, 0);                              \
    STG8(bRow, 32768, 0, 0); STG8(bRow, 32768, 1, 0);                          \
    STG8(bRow, 49152, 0, 64); STG8(bRow, 49152, 1, 64);                        \
    VM4();                                                                     \
    BAR8();                                                                    \
    for (int it = 0; it < NI; ++it) {                                          \
        const int k1 = (2 * it + 1) * 64;                                      \
        const int t2 = 2 * it + 2, t3 = 2 * it + 3;                            \
        const int k2 = (t2 < NT ? t2 : 0) * 64;                                \
        const int k3 = (t3 < NT ? t3 : 0) * 64;                                \
        LDA8(aBE, 0); LDB8(bf0, bBE, 0); STG8(aRow, 16384, 0, k1);             \
        BAR8(); MM8(0, 0, bf0); BAR8();                                        \
        LDB8(bf1, bBE, 1); STG8(aRow, 16384, 1, k1);                           \
        BAR8(); MM8(0, 1, bf1); BAR8();                                        \
        LDA8(aBE, 1); STG8(bRow, 32768, 0, k2);                                \
        BAR8(); MM8(1, 1, bf1); BAR8();                                        \
        STG8(bRow, 32768, 1, k2);                                              \
        BAR8(); MM8(1, 0, bf0); VM4(); BAR8();                                 \
        LDA8(aBO, 0); LDB8(bf0, bBO, 0); STG8(aRow, 0, 0, k2);                 \
        BAR8(); MM8(0, 0, bf0); BAR8();                                        \
        LDB8(bf1, bBO, 1); STG8(aRow, 0, 1, k2);                               \
        BAR8(); MM8(0, 1, bf1); BAR8();                                        \
        LDA8(aBO, 1); STG8(bRow, 49152, 0, k3);                                \
        BAR8(); MM8(1, 1, bf1); BAR8();                                        \
        STG8(bRow, 49152, 1, k3);                                              \
        BAR8(); MM8(1, 0, bf0); VM4(); BAR8();                                 \
    }

// ---------------------------------------------------------------------------
// gemm1_8: h1 = relu(dxp @ W1b^T + b1), K=256 (zero-padded). B rows staged
// permuted (prow = 4*(t&15) + (t>>4)) so lane lam's acc cols jn map to
// n = bn + wn*64 + 4*lam + jn -> natural-layout u16x4 packed stores.
// ---------------------------------------------------------------------------
__global__ __launch_bounds__(512, 2) void gemm1_8(
    const uint16_t* __restrict__ A, const uint16_t* __restrict__ Bw,
    const float* __restrict__ bias, uint16_t* __restrict__ C,
    int M, int N, int K)
{
    __shared__ __align__(16) uint16_t lds[65536];   // 128 KiB
    GEMM8_DECLS()
    const uint16_t* aRow = A + (size_t)(bm + trow) * K + csel;
    const int prow = 4 * (trow & 15) + (trow >> 4);
    const uint16_t* bRow = Bw + (size_t)(bn + prow) * K + csel;
    GEMM8_MAIN()

    float bv[4];
#pragma unroll
    for (int jn = 0; jn < 4; jn++) bv[jn] = bias[bn + wn * 64 + 4 * lam + jn];
#pragma unroll
    for (int im = 0; im < 8; im++) {
#pragma unroll
        for (int r = 0; r < 4; r++) {
            int m = bm + wm * 128 + im * 16 + lad * 4 + r;
            u16x4 o;
#pragma unroll
            for (int jn = 0; jn < 4; jn++)
                o[jn] = f2bf(fmaxf(acc[im][jn][r] + bv[jn], 0.f));
            *(u16x4*)&C[(size_t)m * N + bn + wn * 64 + 4 * lam] = o;
        }
    }
}

// ---------------------------------------------------------------------------
// gemm_fused8: per-row partial of relu(acc + b2) . W3 -> atomicAdd(outacc).
// (B staged unpermuted; n-permutation irrelevant to the reduction.)
// ---------------------------------------------------------------------------
__global__ __launch_bounds__(512, 2) void gemm_fused8(
    const uint16_t* __restrict__ A, const uint16_t* __restrict__ Bw,
    const float* __restrict__ bias, const float* __restrict__ W3,
    float* __restrict__ outacc, int M, int N, int K)
{
    __shared__ __align__(16) uint16_t lds[65536];   // 128 KiB
    GEMM8_DECLS()
    const uint16_t* aRow = A + (size_t)(bm + trow) * K + csel;
    const uint16_t* bRow = Bw + (size_t)(bn + trow) * K + csel;
    GEMM8_MAIN()

    float bv[4], w3v[4];
#pragma unroll
    for (int jn = 0; jn < 4; jn++) {
        int n = bn + wn * 64 + jn * 16 + lam;
        bv[jn] = bias[n];
        w3v[jn] = W3[n];
    }
#pragma unroll
    for (int im = 0; im < 8; im++) {
#pragma unroll
        for (int r = 0; r < 4; r++) {
            float pt = 0.f;
#pragma unroll
            for (int jn = 0; jn < 4; jn++)
                pt += fmaxf(acc[im][jn][r] + bv[jn], 0.f) * w3v[jn];
            pt += __shfl_xor(pt, 1);
            pt += __shfl_xor(pt, 2);
            pt += __shfl_xor(pt, 4);
            pt += __shfl_xor(pt, 8);
            if (lam == 0) {
                int m = bm + wm * 128 + im * 16 + lad * 4 + r;
                atomicAdd(&outacc[m], pt);
            }
        }
    }
}

// ---------------------------------------------------------------------------
// Sigmoid over the accumulated logits. Grid 64 x 256.
// ---------------------------------------------------------------------------
__global__ __launch_bounds__(256) void sigmoid_kernel(
    const float* __restrict__ outacc, float* __restrict__ out)
{
    int b = blockIdx.x * 256 + threadIdx.x;
    out[b] = 1.f / (1.f + __expf(-outacc[b]));
}

// ---------------------------------------------------------------------------
extern "C" void kernel_launch(void* const* d_in, const int* in_sizes, int n_in,
                              void* d_out, int out_size, void* d_ws, size_t ws_size,
                              hipStream_t stream) {
    const int*   sp    = (const int*)d_in[0];
    const float* dense = (const float*)d_in[1];
    const float* ww    = (const float*)d_in[2];
    const float* wb    = (const float*)d_in[3];
    const float* emb   = (const float*)d_in[4];
    const float* W1    = (const float*)d_in[5];
    const float* b1    = (const float*)d_in[6];
    const float* W2    = (const float*)d_in[7];
    const float* b2    = (const float*)d_in[8];
    const float* W3    = (const float*)d_in[9];
    const float* b3    = (const float*)d_in[10];
    float* out = (float*)d_out;

    char* ws = (char*)d_ws;
    float*    wide = (float*)ws;                       //     65,536 B
    uint16_t* dxp  = (uint16_t*)(ws + 65536);          //  8,388,608 B (16384x256)
    uint16_t* W1b  = (uint16_t*)(ws + 8454144);        //    524,288 B (1024x256)
    uint16_t* W2b  = (uint16_t*)(ws + 8978432);        //  2,097,152 B
    uint16_t* h1   = (uint16_t*)(ws + 11075584);       // 33,554,432 B -> 44,630,016 total

    prep_kernel<<<2752, 256, 0, stream>>>(
        sp, dense, emb, W1, W2, ww, wb, b3, dxp, W1b, W2b, wide);
    gemm1_8<<<256, 512, 0, stream>>>(
        dxp, W1b, b1, h1, BATCH, HDIM, K1);
    gemm_fused8<<<256, 512, 0, stream>>>(
        h1, W2b, b2, W3, wide, BATCH, HDIM, HDIM);
    sigmoid_kernel<<<BATCH / 256, 256, 0, stream>>>(wide, out);
}